// Round 10
// baseline (218.144 us; speedup 1.0000x reference)
//
#include <hip/hip_runtime.h>
#include <hip/hip_fp16.h>

namespace {

constexpr int T_STEPS = 256;
constexpr int HD = 50;    // hidden size
constexpr int HP = 64;    // padded hidden
constexpr int KST = 88;   // h-buf row stride in fp16 elems
constexpr int KSTS = 72;  // weight staging stride
constexpr int BT = 16;    // batch tile per block
constexpr int NTHR = 768; // 12 waves: (layer, M-tile)
constexpr int XST = 34;   // xls row stride in floats
constexpr int LAY_SH = BT * KST;     // shorts per (slot, layer)
constexpr int SLOT_SH = 3 * LAY_SH;  // shorts per ring slot

typedef __attribute__((ext_vector_type(8))) _Float16 f16x8;
typedef __attribute__((ext_vector_type(4))) float f32x4;

__device__ __forceinline__ unsigned short f2h(float x) {
  __half h = __float2half(x);  // RNE
  return *reinterpret_cast<unsigned short*>(&h);
}
__device__ __forceinline__ float h2f(unsigned short u) {
  __half h;
  *reinterpret_cast<unsigned short*>(&h) = u;
  return __half2float(h);
}

#define MFMA16 __builtin_amdgcn_mfma_f32_16x16x32_f16

// R8 data path (12 waves = layer x M-tile, fp16 h/W, diagonal 0/2/4, 3-slot ring)
// with the steady-state __syncthreads REPLACED by per-layer LDS progress
// counters: producers release-inc wc[L] after writing h; consumers gate on
//   self RAW : wc[L]   >= 4*(s-8)
//   cross RAW: wc[L-1] >= 4*(s-8)
//   WAR      : wc[L+1] >= 4*(s-9)   (3-slot ring reuse)
// Aggregate counters are sound: the gates bound intra-group drift to <=1 iter.
// Poll values are hoisted into registers one iter early -> common path is a
// register compare (no LDS latency). This desynchronizes wave phases so the
// LDS / VALU / trans / MFMA pipes of different waves interleave instead of
// phase-locking at a barrier (R8: no pipe >65% busy yet iter 1177 cyc).
__global__ __launch_bounds__(NTHR, 3) void rnn3_kernel(
    const float* __restrict__ x,
    const float* __restrict__ Wih1, const float* __restrict__ Whh1,
    const float* __restrict__ bih1, const float* __restrict__ bhh1,
    const float* __restrict__ Wih2, const float* __restrict__ Whh2,
    const float* __restrict__ bih2, const float* __restrict__ bhh2,
    const float* __restrict__ Wih3, const float* __restrict__ Whh3,
    const float* __restrict__ bih3, const float* __restrict__ bhh3,
    const float* __restrict__ fcw, const float* __restrict__ fcb,
    float* __restrict__ out) {
  __shared__ unsigned short hbuf[3 * SLOT_SH];  // [ring][layer][b*KST+k], fp16 bits
  __shared__ float xls[T_STEPS][XST];           // staged x
  __shared__ unsigned short scr[HP * KSTS];     // weight staging (fp16)
  __shared__ int wc[3];                         // per-layer write-progress counters

  const int tid = threadIdx.x;
  const int w = tid >> 6;
  const int myL = w >> 2;        // layer 0..2
  const int wv = w & 3;          // M-tile
  const int lane = tid & 63;
  const int quad = lane >> 4;
  const int l15 = lane & 15;
  const int b0 = blockIdx.x * BT;

  // zero ring slots + counters
  {
    unsigned int* hz = reinterpret_cast<unsigned int*>(hbuf);
    const int n = 3 * SLOT_SH / 2;
    for (int i = tid; i < n; i += NTHR) hz[i] = 0u;
    if (tid < 3) wc[tid] = 0;
  }
  // stage x -> LDS
  for (int idx = tid; idx < BT * T_STEPS; idx += NTHR) {
    int b = idx >> 8, t = idx & 255;
    float2 v = *reinterpret_cast<const float2*>(x + (size_t)(b0 + b) * (T_STEPS * 2) + 2 * t);
    xls[t][2 * b] = v.x;
    xls[t][2 * b + 1] = v.y;
  }

  // ---- stage the five 50x50 matrices as fp16 ----
  const float* mats[5] = {Whh1, Wih2, Whh2, Wih3, Whh3};
  constexpr int matL[5] = {0, 1, 1, 2, 2};
  constexpr int matS[5] = {0, 0, 1, 0, 1};  // slot0 = cross (self for L0), slot1 = self
  f16x8 wA[2][2];  // [slot][kstep]
#pragma unroll
  for (int sl = 0; sl < 2; ++sl)
#pragma unroll
    for (int ks = 0; ks < 2; ++ks) wA[sl][ks] = f16x8(0);

  const int arow = 16 * wv + l15;
#pragma unroll
  for (int m = 0; m < 5; ++m) {
    __syncthreads();
    const float* W = mats[m];
    for (int idx = tid; idx < HP * HP; idx += NTHR) {
      int i = idx >> 6, k = idx & 63;
      float v = (i < HD && k < HD) ? W[i * HD + k] : 0.0f;
      scr[i * KSTS + k] = f2h(v);
    }
    __syncthreads();
    if (myL == matL[m]) {
      const int sl = matS[m];
      const unsigned short* ph = &scr[arow * KSTS + 8 * quad];
      wA[sl][0] = *reinterpret_cast<const f16x8*>(ph);
      wA[sl][1] = *reinterpret_cast<const f16x8*>(ph + 32);
    }
  }

  // per-lane C-row constants
  const int ic = 16 * wv + 4 * quad;
  const float* bi = (myL == 0) ? bih1 : (myL == 1) ? bih2 : bih3;
  const float* bh = (myL == 0) ? bhh1 : (myL == 1) ? bhh2 : bhh3;
  float wx0[4], wx1[4];
  f32x4 bsv;
#pragma unroll
  for (int r = 0; r < 4; ++r) {
    int i = ic + r;
    bool v = i < HD;
    bsv[r] = v ? (bi[i] + bh[i]) : 0.0f;
    wx0[r] = (v && myL == 0) ? Wih1[i * 2 + 0] : 0.0f;
    wx1[r] = (v && myL == 0) ? Wih1[i * 2 + 1] : 0.0f;
  }

  const int selfBuf = myL;
  const int crossBuf = (myL > 0) ? myL - 1 : 0;
  const int ldsOff = l15 * KST + 8 * quad;

  const unsigned short* sbase = hbuf + selfBuf * LAY_SH + ldsOff;
  const unsigned short* cbase = hbuf + crossBuf * LAY_SH + ldsOff;
  unsigned short* wbase = hbuf + myL * LAY_SH + l15 * KST + ic;

  f16x8 pfC0 = f16x8(0), pfC1 = f16x8(0);  // cross B-frags for CURRENT iter

  __syncthreads();

  // ---- shared compute core for one diagonal step (always-active form) ----
  auto core = [&](int s, int wr, int rd) {
    f16x8 bS0 = *reinterpret_cast<const f16x8*>(sbase + rd * SLOT_SH);
    f16x8 bS1 = *reinterpret_cast<const f16x8*>(sbase + rd * SLOT_SH + 32);
    f16x8 pfN0, pfN1;
    if (myL > 0) {
      pfN0 = *reinterpret_cast<const f16x8*>(cbase + rd * SLOT_SH);
      pfN1 = *reinterpret_cast<const f16x8*>(cbase + rd * SLOT_SH + 32);
    }
    f32x4 c;
    if (myL == 0) {
      float2 xc = *reinterpret_cast<const float2*>(&xls[s][2 * l15]);
      f32x4 ci;
#pragma unroll
      for (int r = 0; r < 4; ++r) ci[r] = fmaf(wx1[r], xc.y, fmaf(wx0[r], xc.x, bsv[r]));
      c = MFMA16(wA[0][0], bS0, ci, 0, 0, 0);
      c = MFMA16(wA[0][1], bS1, c, 0, 0, 0);
    } else {
      c = MFMA16(wA[0][0], pfC0, bsv, 0, 0, 0);
      c = MFMA16(wA[0][1], pfC1, c, 0, 0, 0);
      c = MFMA16(wA[1][0], bS0, c, 0, 0, 0);
      c = MFMA16(wA[1][1], bS1, c, 0, 0, 0);
    }
    // batched tanh: ONE rcp for 4 values; clamp keeps product < f32-max
    float d[4];
#pragma unroll
    for (int r = 0; r < 4; ++r) {
      float xr = __builtin_amdgcn_fmed3f(c[r], -11.0f, 11.0f);
      d[r] = __expf(2.0f * xr) + 1.0f;
    }
    float p01 = d[0] * d[1], p23 = d[2] * d[3];
    float rp = __builtin_amdgcn_rcpf(p01 * p23);
    float q01 = rp * p23, q23 = rp * p01;
    float iv[4] = {q01 * d[1], q01 * d[0], q23 * d[3], q23 * d[2]};
    unsigned short ht[4];
#pragma unroll
    for (int r = 0; r < 4; ++r) ht[r] = f2h(fmaf(-2.0f, iv[r], 1.0f));
    unsigned int h01 = (unsigned int)ht[0] | ((unsigned int)ht[1] << 16);
    unsigned int h23 = (unsigned int)ht[2] | ((unsigned int)ht[3] << 16);
    *reinterpret_cast<uint2*>(wbase + wr * SLOT_SH) = make_uint2(h01, h23);
    if (myL > 0) { pfC0 = pfN0; pfC1 = pfN1; }
  };

  auto actOf = [&](int s) {
    return (myL == 0) ? (s < T_STEPS)
         : (myL == 1) ? (s >= 2 && s < T_STEPS + 2)
                      : (s >= 4);
  };

  // barrier-mode step (prologue/epilogue)
  auto stepB = [&](int s, int wr, int rd, bool act) {
    if (act) core(s, wr, rd);
    else if (myL > 0) {  // keep cross prefetch alive through inactive iters
      pfC0 = *reinterpret_cast<const f16x8*>(cbase + rd * SLOT_SH);
      pfC1 = *reinterpret_cast<const f16x8*>(cbase + rd * SLOT_SH + 32);
    }
    __syncthreads();
  };

  // flag-mode step: counters replace the barrier
  int hvS = 0, hvC = 0, hvW = 0;  // hoisted counter snapshots
  auto spin = [&](int idx, int t, int hv) {
    if (hv >= t) return;
    while (__hip_atomic_load(&wc[idx], __ATOMIC_ACQUIRE, __HIP_MEMORY_SCOPE_WORKGROUP) < t) {}
  };
  auto stepF = [&](int s, int wr, int rd, int tgt) {
    spin(myL, tgt, hvS);                          // self RAW (subsumes self WAR)
    if (myL > 0) spin(myL - 1, tgt, hvC);         // cross RAW
    if (myL < 2) spin(myL + 1, tgt - 4, hvW);     // WAR on ring slot
    core(s, wr, rd);
    if (lane == 0)
      __hip_atomic_fetch_add(&wc[myL], 1, __ATOMIC_RELEASE, __HIP_MEMORY_SCOPE_WORKGROUP);
    // hoist next iter's poll values (latency hidden behind this iter's tail)
    hvS = __hip_atomic_load(&wc[myL], __ATOMIC_ACQUIRE, __HIP_MEMORY_SCOPE_WORKGROUP);
    if (myL > 0) hvC = __hip_atomic_load(&wc[myL - 1], __ATOMIC_ACQUIRE, __HIP_MEMORY_SCOPE_WORKGROUP);
    if (myL < 2) hvW = __hip_atomic_load(&wc[myL + 1], __ATOMIC_ACQUIRE, __HIP_MEMORY_SCOPE_WORKGROUP);
  };

  // prologue s=0..7 (barriers; all act-windows saturate by s=8)
  for (int s = 0; s < 8; ++s) stepB(s, s % 3, (s + 2) % 3, actOf(s));
  // flag window s=8..247 (240 iters = 80 groups of 3, literal ring slots)
  int tgt = 0;  // 4*(s-8)
  for (int g = 0; g < 80; ++g) {
    int s = 8 + 3 * g;               // s%3 = 2
    stepF(s,     2, 1, tgt);
    stepF(s + 1, 0, 2, tgt + 4);     // s%3 = 0
    stepF(s + 2, 1, 0, tgt + 8);     // s%3 = 1
    tgt += 12;
  }
  __syncthreads();  // transition: re-align before act-gated epilogue
  // epilogue s=248..259 (barriers)
  for (int s = 248; s < 260; ++s) stepB(s, s % 3, (s + 2) % 3, actOf(s));

  // ---- fc epilogue: h3_255 written at s=259 -> slot 259%3 = 1 ----
  if (tid < BT * 2) {
    int b = tid >> 1, o = tid & 1;
    const unsigned short* h3 = hbuf + 1 * SLOT_SH + 2 * LAY_SH + b * KST;
    float acc = fcb[o];
    for (int i = 0; i < HD; ++i) acc += fcw[o * HD + i] * h2f(h3[i]);
    out[(size_t)(b0 + b) * 2 + o] = acc;
  }
}

}  // namespace

extern "C" void kernel_launch(void* const* d_in, const int* in_sizes, int n_in,
                              void* d_out, int out_size, void* d_ws, size_t ws_size,
                              hipStream_t stream) {
  const float* x = (const float*)d_in[0];
  const float* Wih1 = (const float*)d_in[1];
  const float* Whh1 = (const float*)d_in[2];
  const float* bih1 = (const float*)d_in[3];
  const float* bhh1 = (const float*)d_in[4];
  const float* Wih2 = (const float*)d_in[5];
  const float* Whh2 = (const float*)d_in[6];
  const float* bih2 = (const float*)d_in[7];
  const float* bhh2 = (const float*)d_in[8];
  const float* Wih3 = (const float*)d_in[9];
  const float* Whh3 = (const float*)d_in[10];
  const float* bih3 = (const float*)d_in[11];
  const float* bhh3 = (const float*)d_in[12];
  const float* fcw = (const float*)d_in[13];
  const float* fcb = (const float*)d_in[14];

  rnn3_kernel<<<4096 / BT, NTHR, 0, stream>>>(x, Wih1, Whh1, bih1, bhh1,
                                              Wih2, Whh2, bih2, bhh2,
                                              Wih3, Whh3, bih3, bhh3,
                                              fcw, fcb, (float*)d_out);
}

// Round 11
// 196.722 us; speedup vs baseline: 1.1089x; 1.1089x over previous
//
#include <hip/hip_runtime.h>
#include <hip/hip_fp16.h>

namespace {

constexpr int T_STEPS = 256;
constexpr int HD = 50;    // hidden size
constexpr int HP = 64;    // padded hidden
constexpr int KST = 88;   // h-buf row stride in fp16 elems
constexpr int KSTS = 72;  // weight staging stride
constexpr int BT = 16;    // batch tile per block
constexpr int NTHR = 768; // 12 waves: (layer, M-tile) — measured-best config
constexpr int XST = 34;   // xls row stride in floats
constexpr int LAY_SH = BT * KST;     // shorts per (slot, layer)
constexpr int SLOT_SH = 3 * LAY_SH;  // shorts per ring slot

typedef __attribute__((ext_vector_type(8))) _Float16 f16x8;
typedef __attribute__((ext_vector_type(4))) float f32x4;

__device__ __forceinline__ unsigned short f2h(float x) {
  __half h = __float2half(x);  // RNE
  return *reinterpret_cast<unsigned short*>(&h);
}
__device__ __forceinline__ float h2f(unsigned short u) {
  __half h;
  *reinterpret_cast<unsigned short*>(&h) = u;
  return __half2float(h);
}

#define MFMA16 __builtin_amdgcn_mfma_f32_16x16x32_f16

// R8 skeleton (12 waves = layer x M-tile, fp16 h/W, diagonal 0/2/4, 3-slot
// ring, literal-slot unroll, per-iter barrier) with critical-path shaping:
//  - cross-prefetch reads moved AFTER the h-write (off the post-barrier LDS
//    queue that the critical self-reads share)
//  - L1/L2 MFMA split: self 2-chain (gated on bS) || cross 2-chain (operands
//    in regs from last iter) + merge add — barrier-to-write path ~40cyc shorter
//  - L0 x-value prefetched one iter ahead into a register
__global__ __launch_bounds__(NTHR, 3) void rnn3_kernel(
    const float* __restrict__ x,
    const float* __restrict__ Wih1, const float* __restrict__ Whh1,
    const float* __restrict__ bih1, const float* __restrict__ bhh1,
    const float* __restrict__ Wih2, const float* __restrict__ Whh2,
    const float* __restrict__ bih2, const float* __restrict__ bhh2,
    const float* __restrict__ Wih3, const float* __restrict__ Whh3,
    const float* __restrict__ bih3, const float* __restrict__ bhh3,
    const float* __restrict__ fcw, const float* __restrict__ fcb,
    float* __restrict__ out) {
  __shared__ unsigned short hbuf[3 * SLOT_SH];  // [ring][layer][b*KST+k], fp16 bits
  __shared__ float xls[T_STEPS][XST];           // staged x
  __shared__ unsigned short scr[HP * KSTS];     // weight staging (fp16)

  const int tid = threadIdx.x;
  const int w = tid >> 6;
  const int myL = w >> 2;        // layer 0..2
  const int wv = w & 3;          // M-tile
  const int lane = tid & 63;
  const int quad = lane >> 4;
  const int l15 = lane & 15;
  const int b0 = blockIdx.x * BT;

  // zero all 3 ring slots (initial h=0 and the k>=HD pad)
  {
    unsigned int* hz = reinterpret_cast<unsigned int*>(hbuf);
    const int n = 3 * SLOT_SH / 2;
    for (int i = tid; i < n; i += NTHR) hz[i] = 0u;
  }
  // stage x -> LDS
  for (int idx = tid; idx < BT * T_STEPS; idx += NTHR) {
    int b = idx >> 8, t = idx & 255;
    float2 v = *reinterpret_cast<const float2*>(x + (size_t)(b0 + b) * (T_STEPS * 2) + 2 * t);
    xls[t][2 * b] = v.x;
    xls[t][2 * b + 1] = v.y;
  }

  // ---- stage the five 50x50 matrices as fp16 ----
  const float* mats[5] = {Whh1, Wih2, Whh2, Wih3, Whh3};
  constexpr int matL[5] = {0, 1, 1, 2, 2};
  constexpr int matS[5] = {0, 0, 1, 0, 1};  // slot0 = cross (self for L0), slot1 = self
  f16x8 wA[2][2];  // [slot][kstep]
#pragma unroll
  for (int sl = 0; sl < 2; ++sl)
#pragma unroll
    for (int ks = 0; ks < 2; ++ks) wA[sl][ks] = f16x8(0);

  const int arow = 16 * wv + l15;
#pragma unroll
  for (int m = 0; m < 5; ++m) {
    __syncthreads();
    const float* W = mats[m];
    for (int idx = tid; idx < HP * HP; idx += NTHR) {
      int i = idx >> 6, k = idx & 63;
      float v = (i < HD && k < HD) ? W[i * HD + k] : 0.0f;
      scr[i * KSTS + k] = f2h(v);
    }
    __syncthreads();
    if (myL == matL[m]) {
      const int sl = matS[m];
      const unsigned short* ph = &scr[arow * KSTS + 8 * quad];
      wA[sl][0] = *reinterpret_cast<const f16x8*>(ph);
      wA[sl][1] = *reinterpret_cast<const f16x8*>(ph + 32);
    }
  }

  // per-lane C-row constants
  const int ic = 16 * wv + 4 * quad;
  const float* bi = (myL == 0) ? bih1 : (myL == 1) ? bih2 : bih3;
  const float* bh = (myL == 0) ? bhh1 : (myL == 1) ? bhh2 : bhh3;
  float wx0[4], wx1[4];
  f32x4 bsv;
#pragma unroll
  for (int r = 0; r < 4; ++r) {
    int i = ic + r;
    bool v = i < HD;
    bsv[r] = v ? (bi[i] + bh[i]) : 0.0f;
    wx0[r] = (v && myL == 0) ? Wih1[i * 2 + 0] : 0.0f;
    wx1[r] = (v && myL == 0) ? Wih1[i * 2 + 1] : 0.0f;
  }

  const int selfBuf = myL;
  const int crossBuf = (myL > 0) ? myL - 1 : 0;
  const int ldsOff = l15 * KST + 8 * quad;

  const unsigned short* sbase = hbuf + selfBuf * LAY_SH + ldsOff;
  const unsigned short* cbase = hbuf + crossBuf * LAY_SH + ldsOff;
  unsigned short* wbase = hbuf + myL * LAY_SH + l15 * KST + ic;

  f16x8 pfC0 = f16x8(0), pfC1 = f16x8(0);  // cross B-frags for CURRENT iter
  const f32x4 zero4 = {0.f, 0.f, 0.f, 0.f};

  __syncthreads();
  float2 xcur = (myL == 0) ? *reinterpret_cast<const float2*>(&xls[0][2 * l15])
                           : make_float2(0.f, 0.f);

  // one diagonal step: iter s computes h1_s, h2_{s-2}, h3_{s-4}
  auto core = [&](int s, int wr, int rd) {
    // critical self-reads first (nothing else queued ahead post-barrier)
    f16x8 bS0 = *reinterpret_cast<const f16x8*>(sbase + rd * SLOT_SH);
    f16x8 bS1 = *reinterpret_cast<const f16x8*>(sbase + rd * SLOT_SH + 32);
    f32x4 c;
    if (myL == 0) {
      f32x4 ci;
#pragma unroll
      for (int r = 0; r < 4; ++r) ci[r] = fmaf(wx1[r], xcur.y, fmaf(wx0[r], xcur.x, bsv[r]));
      c = MFMA16(wA[0][0], bS0, ci, 0, 0, 0);
      c = MFMA16(wA[0][1], bS1, c, 0, 0, 0);
      int sn = (s + 1 < T_STEPS) ? s + 1 : T_STEPS - 1;
      xcur = *reinterpret_cast<const float2*>(&xls[sn][2 * l15]);  // prefetch next x
    } else {
      // cross 2-chain: operands already in registers, starts immediately
      f32x4 cc = MFMA16(wA[0][0], pfC0, bsv, 0, 0, 0);
      cc = MFMA16(wA[0][1], pfC1, cc, 0, 0, 0);
      // self 2-chain: gated on bS (the critical path)
      f32x4 cs = MFMA16(wA[1][0], bS0, zero4, 0, 0, 0);
      cs = MFMA16(wA[1][1], bS1, cs, 0, 0, 0);
#pragma unroll
      for (int r = 0; r < 4; ++r) c[r] = cc[r] + cs[r];
    }
    // batched tanh: ONE rcp for 4 values; clamp keeps product < f32-max
    float d[4];
#pragma unroll
    for (int r = 0; r < 4; ++r) {
      float xr = __builtin_amdgcn_fmed3f(c[r], -11.0f, 11.0f);
      d[r] = __expf(2.0f * xr) + 1.0f;
    }
    float p01 = d[0] * d[1], p23 = d[2] * d[3];
    float rp = __builtin_amdgcn_rcpf(p01 * p23);
    float q01 = rp * p23, q23 = rp * p01;
    float iv[4] = {q01 * d[1], q01 * d[0], q23 * d[3], q23 * d[2]};
    unsigned short ht[4];
#pragma unroll
    for (int r = 0; r < 4; ++r) ht[r] = f2h(fmaf(-2.0f, iv[r], 1.0f));
    unsigned int h01 = (unsigned int)ht[0] | ((unsigned int)ht[1] << 16);
    unsigned int h23 = (unsigned int)ht[2] | ((unsigned int)ht[3] << 16);
    *reinterpret_cast<uint2*>(wbase + wr * SLOT_SH) = make_uint2(h01, h23);
    // non-critical cross prefetch AFTER the write: full barrier-to-MFMA window
    // to complete; keeps the post-barrier LDS queue clear for bS reads.
    if (myL > 0) {
      pfC0 = *reinterpret_cast<const f16x8*>(cbase + rd * SLOT_SH);
      pfC1 = *reinterpret_cast<const f16x8*>(cbase + rd * SLOT_SH + 32);
    }
  };

  auto actOf = [&](int s) {
    return (myL == 0) ? (s < T_STEPS)
         : (myL == 1) ? (s >= 2 && s < T_STEPS + 2)
                      : (s >= 4);
  };

  auto stepB = [&](int s, int wr, int rd, bool act) {
    if (act) core(s, wr, rd);
    else if (myL > 0) {  // keep cross prefetch alive through inactive iters
      pfC0 = *reinterpret_cast<const f16x8*>(cbase + rd * SLOT_SH);
      pfC1 = *reinterpret_cast<const f16x8*>(cbase + rd * SLOT_SH + 32);
    }
    __syncthreads();
  };

  // prologue s=0..3
  for (int s = 0; s < 4; ++s) stepB(s, s % 3, (s + 2) % 3, actOf(s));
  // steady s=4..255: all waves active; literal ring slots
  for (int sb = 4; sb < 256; sb += 3) {
    core(sb + 0, 1, 0); __syncthreads();
    core(sb + 1, 2, 1); __syncthreads();
    core(sb + 2, 0, 2); __syncthreads();
  }
  // epilogue s=256..259
  for (int s = 256; s < 260; ++s) stepB(s, s % 3, (s + 2) % 3, actOf(s));

  // ---- fc epilogue: h3_255 written at s=259 -> slot 259%3 = 1 ----
  if (tid < BT * 2) {
    int b = tid >> 1, o = tid & 1;
    const unsigned short* h3 = hbuf + 1 * SLOT_SH + 2 * LAY_SH + b * KST;
    float acc = fcb[o];
    for (int i = 0; i < HD; ++i) acc += fcw[o * HD + i] * h2f(h3[i]);
    out[(size_t)(b0 + b) * 2 + o] = acc;
  }
}

}  // namespace

extern "C" void kernel_launch(void* const* d_in, const int* in_sizes, int n_in,
                              void* d_out, int out_size, void* d_ws, size_t ws_size,
                              hipStream_t stream) {
  const float* x = (const float*)d_in[0];
  const float* Wih1 = (const float*)d_in[1];
  const float* Whh1 = (const float*)d_in[2];
  const float* bih1 = (const float*)d_in[3];
  const float* bhh1 = (const float*)d_in[4];
  const float* Wih2 = (const float*)d_in[5];
  const float* Whh2 = (const float*)d_in[6];
  const float* bih2 = (const float*)d_in[7];
  const float* bhh2 = (const float*)d_in[8];
  const float* Wih3 = (const float*)d_in[9];
  const float* Whh3 = (const float*)d_in[10];
  const float* bih3 = (const float*)d_in[11];
  const float* bhh3 = (const float*)d_in[12];
  const float* fcw = (const float*)d_in[13];
  const float* fcb = (const float*)d_in[14];

  rnn3_kernel<<<4096 / BT, NTHR, 0, stream>>>(x, Wih1, Whh1, bih1, bhh1,
                                              Wih2, Whh2, bih2, bhh2,
                                              Wih3, Whh3, bih3, bhh3,
                                              fcw, fcb, (float*)d_out);
}

// Round 12
// 191.745 us; speedup vs baseline: 1.1377x; 1.0260x over previous
//
#include <hip/hip_runtime.h>
#include <hip/hip_fp16.h>

namespace {

constexpr int T_STEPS = 256;
constexpr int HD = 50;    // hidden size
constexpr int HP = 64;    // padded hidden
constexpr int KST = 88;   // h-buf row stride in fp16 elems
constexpr int KSTS = 72;  // weight staging stride
constexpr int BT = 16;    // batch tile per block
constexpr int NTHR = 768; // 12 waves: (layer, M-tile) — measured-best config
constexpr int XST = 34;   // xls row stride in floats
constexpr int LAY_SH = BT * KST;     // shorts per (slot, layer)
constexpr int SLOT_SH = 3 * LAY_SH;  // shorts per ring slot

typedef __attribute__((ext_vector_type(8))) _Float16 f16x8;
typedef __attribute__((ext_vector_type(4))) float f32x4;

__device__ __forceinline__ unsigned short f2h(float x) {
  __half h = __float2half(x);  // RNE
  return *reinterpret_cast<unsigned short*>(&h);
}
__device__ __forceinline__ float h2f(unsigned short u) {
  __half h;
  *reinterpret_cast<unsigned short*>(&h) = u;
  return __half2float(h);
}

#define MFMA16 __builtin_amdgcn_mfma_f32_16x16x32_f16

// Raw workgroup barrier WITHOUT the lgkmcnt(0) drain that __syncthreads emits.
// Safe here because: a DS op enters the CU's LDS pipe at ISSUE in program
// order; consumer reads issue only after barrier release, i.e. after all
// producers' writes are already enqueued; per-bank FIFO processing then gives
// read-after-write visibility. Compiler still waits on each wave's OWN loads.
__device__ __forceinline__ void barrier_nodrain() {
  asm volatile("s_barrier" ::: "memory");
}

// R8 skeleton: 12 waves = layer x M-tile, fp16 h/W (W single fp16), diagonal
// offsets 0/2/4, 3-slot ring, literal-slot steady-state unroll, batched-rcp
// tanh. R11 change: steady-state __syncthreads -> raw s_barrier (no drain).
__global__ __launch_bounds__(NTHR, 3) void rnn3_kernel(
    const float* __restrict__ x,
    const float* __restrict__ Wih1, const float* __restrict__ Whh1,
    const float* __restrict__ bih1, const float* __restrict__ bhh1,
    const float* __restrict__ Wih2, const float* __restrict__ Whh2,
    const float* __restrict__ bih2, const float* __restrict__ bhh2,
    const float* __restrict__ Wih3, const float* __restrict__ Whh3,
    const float* __restrict__ bih3, const float* __restrict__ bhh3,
    const float* __restrict__ fcw, const float* __restrict__ fcb,
    float* __restrict__ out) {
  __shared__ unsigned short hbuf[3 * SLOT_SH];  // [ring][layer][b*KST+k], fp16 bits
  __shared__ float xls[T_STEPS][XST];           // staged x
  __shared__ unsigned short scr[HP * KSTS];     // weight staging (fp16)

  const int tid = threadIdx.x;
  const int w = tid >> 6;
  const int myL = w >> 2;        // layer 0..2
  const int wv = w & 3;          // M-tile
  const int lane = tid & 63;
  const int quad = lane >> 4;
  const int l15 = lane & 15;
  const int b0 = blockIdx.x * BT;

  // zero all 3 ring slots (initial h=0 and the k>=HD pad)
  {
    unsigned int* hz = reinterpret_cast<unsigned int*>(hbuf);
    const int n = 3 * SLOT_SH / 2;
    for (int i = tid; i < n; i += NTHR) hz[i] = 0u;
  }
  // stage x -> LDS
  for (int idx = tid; idx < BT * T_STEPS; idx += NTHR) {
    int b = idx >> 8, t = idx & 255;
    float2 v = *reinterpret_cast<const float2*>(x + (size_t)(b0 + b) * (T_STEPS * 2) + 2 * t);
    xls[t][2 * b] = v.x;
    xls[t][2 * b + 1] = v.y;
  }

  // ---- stage the five 50x50 matrices as fp16 ----
  const float* mats[5] = {Whh1, Wih2, Whh2, Wih3, Whh3};
  constexpr int matL[5] = {0, 1, 1, 2, 2};
  constexpr int matS[5] = {0, 0, 1, 0, 1};  // slot0 = cross (self for L0), slot1 = self
  f16x8 wA[2][2];  // [slot][kstep]
#pragma unroll
  for (int sl = 0; sl < 2; ++sl)
#pragma unroll
    for (int ks = 0; ks < 2; ++ks) wA[sl][ks] = f16x8(0);

  const int arow = 16 * wv + l15;
#pragma unroll
  for (int m = 0; m < 5; ++m) {
    __syncthreads();
    const float* W = mats[m];
    for (int idx = tid; idx < HP * HP; idx += NTHR) {
      int i = idx >> 6, k = idx & 63;
      float v = (i < HD && k < HD) ? W[i * HD + k] : 0.0f;
      scr[i * KSTS + k] = f2h(v);
    }
    __syncthreads();
    if (myL == matL[m]) {
      const int sl = matS[m];
      const unsigned short* ph = &scr[arow * KSTS + 8 * quad];
      wA[sl][0] = *reinterpret_cast<const f16x8*>(ph);
      wA[sl][1] = *reinterpret_cast<const f16x8*>(ph + 32);
    }
  }

  // per-lane C-row constants
  const int ic = 16 * wv + 4 * quad;
  const float* bi = (myL == 0) ? bih1 : (myL == 1) ? bih2 : bih3;
  const float* bh = (myL == 0) ? bhh1 : (myL == 1) ? bhh2 : bhh3;
  float wx0[4], wx1[4];
  f32x4 bsv;
#pragma unroll
  for (int r = 0; r < 4; ++r) {
    int i = ic + r;
    bool v = i < HD;
    bsv[r] = v ? (bi[i] + bh[i]) : 0.0f;
    wx0[r] = (v && myL == 0) ? Wih1[i * 2 + 0] : 0.0f;
    wx1[r] = (v && myL == 0) ? Wih1[i * 2 + 1] : 0.0f;
  }

  const int selfBuf = myL;
  const int crossBuf = (myL > 0) ? myL - 1 : 0;
  const int ldsOff = l15 * KST + 8 * quad;

  const unsigned short* sbase = hbuf + selfBuf * LAY_SH + ldsOff;
  const unsigned short* cbase = hbuf + crossBuf * LAY_SH + ldsOff;
  unsigned short* wbase = hbuf + myL * LAY_SH + l15 * KST + ic;

  f16x8 pfC0 = f16x8(0), pfC1 = f16x8(0);  // cross B-frags for CURRENT iter

  __syncthreads();

  // ---- compute core for one diagonal step (R8 form) ----
  auto core = [&](int s, int wr, int rd) {
    f16x8 bS0 = *reinterpret_cast<const f16x8*>(sbase + rd * SLOT_SH);
    f16x8 bS1 = *reinterpret_cast<const f16x8*>(sbase + rd * SLOT_SH + 32);
    f16x8 pfN0, pfN1;
    if (myL > 0) {  // prefetch cross frags for NEXT iter
      pfN0 = *reinterpret_cast<const f16x8*>(cbase + rd * SLOT_SH);
      pfN1 = *reinterpret_cast<const f16x8*>(cbase + rd * SLOT_SH + 32);
    }
    f32x4 c;
    if (myL == 0) {
      float2 xc = *reinterpret_cast<const float2*>(&xls[s][2 * l15]);
      f32x4 ci;
#pragma unroll
      for (int r = 0; r < 4; ++r) ci[r] = fmaf(wx1[r], xc.y, fmaf(wx0[r], xc.x, bsv[r]));
      c = MFMA16(wA[0][0], bS0, ci, 0, 0, 0);
      c = MFMA16(wA[0][1], bS1, c, 0, 0, 0);
    } else {
      c = MFMA16(wA[0][0], pfC0, bsv, 0, 0, 0);
      c = MFMA16(wA[0][1], pfC1, c, 0, 0, 0);
      c = MFMA16(wA[1][0], bS0, c, 0, 0, 0);
      c = MFMA16(wA[1][1], bS1, c, 0, 0, 0);
    }
    // batched tanh: ONE rcp for 4 values; clamp keeps product < f32-max
    float d[4];
#pragma unroll
    for (int r = 0; r < 4; ++r) {
      float xr = __builtin_amdgcn_fmed3f(c[r], -11.0f, 11.0f);
      d[r] = __expf(2.0f * xr) + 1.0f;
    }
    float p01 = d[0] * d[1], p23 = d[2] * d[3];
    float rp = __builtin_amdgcn_rcpf(p01 * p23);
    float q01 = rp * p23, q23 = rp * p01;
    float iv[4] = {q01 * d[1], q01 * d[0], q23 * d[3], q23 * d[2]};
    unsigned short ht[4];
#pragma unroll
    for (int r = 0; r < 4; ++r) ht[r] = f2h(fmaf(-2.0f, iv[r], 1.0f));
    unsigned int h01 = (unsigned int)ht[0] | ((unsigned int)ht[1] << 16);
    unsigned int h23 = (unsigned int)ht[2] | ((unsigned int)ht[3] << 16);
    *reinterpret_cast<uint2*>(wbase + wr * SLOT_SH) = make_uint2(h01, h23);
    if (myL > 0) { pfC0 = pfN0; pfC1 = pfN1; }
  };

  auto actOf = [&](int s) {
    return (myL == 0) ? (s < T_STEPS)
         : (myL == 1) ? (s >= 2 && s < T_STEPS + 2)
                      : (s >= 4);
  };

  // barrier-mode step (prologue/epilogue): full __syncthreads for safety
  auto stepB = [&](int s, int wr, int rd, bool act) {
    if (act) core(s, wr, rd);
    else if (myL > 0) {  // keep cross prefetch alive through inactive iters
      pfC0 = *reinterpret_cast<const f16x8*>(cbase + rd * SLOT_SH);
      pfC1 = *reinterpret_cast<const f16x8*>(cbase + rd * SLOT_SH + 32);
    }
    __syncthreads();
  };

  // prologue s=0..3
  for (int s = 0; s < 4; ++s) stepB(s, s % 3, (s + 2) % 3, actOf(s));
  // steady s=4..255: all waves active; literal ring slots; NO-DRAIN barrier
  for (int sb = 4; sb < 256; sb += 3) {
    core(sb + 0, 1, 0); barrier_nodrain();
    core(sb + 1, 2, 1); barrier_nodrain();
    core(sb + 2, 0, 2); barrier_nodrain();
  }
  __syncthreads();  // re-establish full ordering before act-gated epilogue
  // epilogue s=256..259
  for (int s = 256; s < 260; ++s) stepB(s, s % 3, (s + 2) % 3, actOf(s));

  // ---- fc epilogue: h3_255 written at s=259 -> slot 259%3 = 1 ----
  if (tid < BT * 2) {
    int b = tid >> 1, o = tid & 1;
    const unsigned short* h3 = hbuf + 1 * SLOT_SH + 2 * LAY_SH + b * KST;
    float acc = fcb[o];
    for (int i = 0; i < HD; ++i) acc += fcw[o * HD + i] * h2f(h3[i]);
    out[(size_t)(b0 + b) * 2 + o] = acc;
  }
}

}  // namespace

extern "C" void kernel_launch(void* const* d_in, const int* in_sizes, int n_in,
                              void* d_out, int out_size, void* d_ws, size_t ws_size,
                              hipStream_t stream) {
  const float* x = (const float*)d_in[0];
  const float* Wih1 = (const float*)d_in[1];
  const float* Whh1 = (const float*)d_in[2];
  const float* bih1 = (const float*)d_in[3];
  const float* bhh1 = (const float*)d_in[4];
  const float* Wih2 = (const float*)d_in[5];
  const float* Whh2 = (const float*)d_in[6];
  const float* bih2 = (const float*)d_in[7];
  const float* bhh2 = (const float*)d_in[8];
  const float* Wih3 = (const float*)d_in[9];
  const float* Whh3 = (const float*)d_in[10];
  const float* bih3 = (const float*)d_in[11];
  const float* bhh3 = (const float*)d_in[12];
  const float* fcw = (const float*)d_in[13];
  const float* fcb = (const float*)d_in[14];

  rnn3_kernel<<<4096 / BT, NTHR, 0, stream>>>(x, Wih1, Whh1, bih1, bhh1,
                                              Wih2, Whh2, bih2, bhh2,
                                              Wih3, Whh3, bih3, bhh3,
                                              fcw, fcb, (float*)d_out);
}